// Round 3
// baseline (1093.138 us; speedup 1.0000x reference)
//
#include <hip/hip_runtime.h>

#define T       512
#define DIN     32
#define HCELLS  64
#define NB      16      // batch elems per block (MFMA N dim)
#define TB      256     // 4 waves
#define GRID    64      // 1024 / NB

typedef _Float16 half8  __attribute__((ext_vector_type(8)));
typedef _Float16 half4v __attribute__((ext_vector_type(4)));
typedef _Float16 half2v __attribute__((ext_vector_type(2)));
typedef float    float4v __attribute__((ext_vector_type(4)));

// LDS B-operand buffers (fp16), stride 40 halves per n-row
#define STRIDE  40
#define B0H_OFF 0                   // [2][3][16][40]  x | h0 (layer-0 B)
#define B0L_OFF (2*3*16*STRIDE)
#define B1H_OFF (B0L_OFF + 2*3*16*STRIDE)   // [2][4][16][40]  h0 | h1 (layer-1 B)
#define B1L_OFF (B1H_OFF + 2*4*16*STRIDE)
#define SB_HALFS (B1L_OFF + 2*4*16*STRIDE)

__device__ __forceinline__ int idx0(int p, int kt, int n, int k) {
    return ((p * 3 + kt) * 16 + n) * STRIDE + k;
}
__device__ __forceinline__ int idx1(int p, int kt, int n, int k) {
    return ((p * 4 + kt) * 16 + n) * STRIDE + k;
}

// split fp32 -> (hi, lo) fp16 pair
__device__ __forceinline__ void split8(const float* v, half8& hi, half8& lo) {
    #pragma unroll
    for (int e = 0; e < 8; ++e) {
        _Float16 h = (_Float16)v[e];
        hi[e] = h;
        lo[e] = (_Float16)(v[e] - (float)h);
    }
}

// merged-rcp LSTM cell update: 5 exp + 2 rcp per element (was 5 exp + 5 rcp)
//   c' = sigm(zf)*c + sigm(zi)*tanh(zg) = [c*I*Gp + F*Gm] / (F*I*Gp)
//   h  = sigm(zo)*tanh(c')              = Cm / (O*Cp)
__device__ __forceinline__ void cell_update(const float4v acc[4], float* c,
                                            half4v& hh, half4v& hl, float* hout)
{
    #pragma unroll
    for (int r = 0; r < 4; ++r) {
        float ei = __expf(-acc[0][r]);
        float ef = __expf(-acc[1][r]);
        float G2 = __expf(2.0f * acc[2][r]);
        float I = 1.0f + ei, F = 1.0f + ef;
        float Gp = G2 + 1.0f, Gm = G2 - 1.0f;
        float P = I * Gp;
        float num = fmaf(F, Gm, c[r] * P);
        float cn = num * __builtin_amdgcn_rcpf(F * P);
        cn = fminf(fmaxf(cn, -40.0f), 40.0f);   // NaN insurance; tanh(40)==1 in fp32
        c[r] = cn;
        float eo = __expf(-acc[3][r]);
        float C2 = __expf(2.0f * cn);
        float O = 1.0f + eo;
        float Cp = C2 + 1.0f, Cm = C2 - 1.0f;
        float h = Cm * __builtin_amdgcn_rcpf(O * Cp);
        if (hout) hout[r] = h;
        _Float16 h16 = (_Float16)h;
        hh[r] = h16;
        hl[r] = (_Float16)(h - (float)h16);
    }
}

__global__ void __launch_bounds__(TB, 1)
lstm2_mfma_kernel(const float* __restrict__ x,
                  const float* __restrict__ Wih0, const float* __restrict__ Whh0,
                  const float* __restrict__ bih0, const float* __restrict__ bhh0,
                  const float* __restrict__ Wih1, const float* __restrict__ Whh1,
                  const float* __restrict__ bih1, const float* __restrict__ bhh1,
                  const float* __restrict__ W1,   const float* __restrict__ b1,
                  const float* __restrict__ W2,   const float* __restrict__ b2,
                  float* __restrict__ out)
{
    const int tid  = threadIdx.x;
    const int w    = tid >> 6;          // wave 0..3
    const int lane = tid & 63;
    const int n16  = lane & 15;         // MFMA free-index / local batch
    const int q    = lane >> 4;         // quad 0..3
    const int j0   = w * 16 + q * 4;    // this thread's hidden-unit base (4 rows)
    const int b0   = blockIdx.x * NB;   // global batch base

    __shared__ __align__(16) _Float16 SB[SB_HALFS];
    __shared__ __align__(16) float HS[16 * 68 + 16 * 33];  // head scratch

    // ---------------- A-fragments (weights, hi/lo fp16) in registers ----------------
    half8 a0h[4][3], a0l[4][3];   // layer0: K = 96 (x 32 | h0 64)
    half8 a1h[4][4], a1l[4][4];   // layer1: K = 128 (h0 64 | h1 64)
    float4v bias0v[4], bias1v[4];

    #pragma unroll
    for (int l = 0; l < 4; ++l) {
        const int row = (l * 4 + w) * 16 + n16;
        float v[8];
        {
            const float4* p = (const float4*)(Wih0 + row * DIN + q * 8);
            float4 u0 = p[0], u1 = p[1];
            v[0]=u0.x; v[1]=u0.y; v[2]=u0.z; v[3]=u0.w;
            v[4]=u1.x; v[5]=u1.y; v[6]=u1.z; v[7]=u1.w;
            split8(v, a0h[l][0], a0l[l][0]);
        }
        #pragma unroll
        for (int kt = 1; kt < 3; ++kt) {
            const float4* p = (const float4*)(Whh0 + row * HCELLS + (kt - 1) * 32 + q * 8);
            float4 u0 = p[0], u1 = p[1];
            v[0]=u0.x; v[1]=u0.y; v[2]=u0.z; v[3]=u0.w;
            v[4]=u1.x; v[5]=u1.y; v[6]=u1.z; v[7]=u1.w;
            split8(v, a0h[l][kt], a0l[l][kt]);
        }
        #pragma unroll
        for (int kt = 0; kt < 4; ++kt) {
            const float* base = (kt < 2) ? (Wih1 + row * HCELLS + kt * 32)
                                         : (Whh1 + row * HCELLS + (kt - 2) * 32);
            const float4* p = (const float4*)(base + q * 8);
            float4 u0 = p[0], u1 = p[1];
            v[0]=u0.x; v[1]=u0.y; v[2]=u0.z; v[3]=u0.w;
            v[4]=u1.x; v[5]=u1.y; v[6]=u1.z; v[7]=u1.w;
            split8(v, a1h[l][kt], a1l[l][kt]);
        }
        const int r0 = l * 64 + j0;
        float4v bi = *(const float4v*)(bih0 + r0);
        float4v bh = *(const float4v*)(bhh0 + r0);
        bias0v[l] = bi + bh;
        bi = *(const float4v*)(bih1 + r0);
        bh = *(const float4v*)(bhh1 + r0);
        bias1v[l] = bi + bh;
    }

    // ---------------- zero LDS, stage x(0) and x(1) ----------------
    for (int i = tid; i < SB_HALFS / 2; i += TB) ((int*)SB)[i] = 0;

    const int nx = tid >> 4;            // x-loader: batch 0..15
    const int kp = (tid & 15) * 2;      // x-loader: k pair 0..30
    const float* xp0 = x + (size_t)(b0 + nx) * T * DIN + kp;
    __syncthreads();
    #pragma unroll
    for (int t0 = 0; t0 < 2; ++t0) {
        float2 xv = *(const float2*)(xp0 + t0 * DIN);
        _Float16 hx0 = (_Float16)xv.x, hx1 = (_Float16)xv.y;
        half2v hi = {hx0, hx1};
        half2v lo = {(_Float16)(xv.x - (float)hx0), (_Float16)(xv.y - (float)hx1)};
        *(half2v*)&SB[B0H_OFF + idx0(t0, 0, nx, kp)] = hi;
        *(half2v*)&SB[B0L_OFF + idx0(t0, 0, nx, kp)] = lo;
    }
    __syncthreads();

    float c0r[4] = {0, 0, 0, 0}, c1r[4] = {0, 0, 0, 0};
    float hlast[4];

    const int ktw0 = 1 + (j0 >> 5);     // h0 slot in B0 (k = 32 + j)
    const int ktw1 = (j0 >> 5);         // h0 slot in B1 (k = j)
    const int kk   = j0 & 31;

    // ---------------- preamble: L0(0) -> h0(parity 1) ----------------
    {
        float4v acc[4];
        #pragma unroll
        for (int l = 0; l < 4; ++l) acc[l] = bias0v[l];
        #pragma unroll
        for (int kt = 0; kt < 3; ++kt) {
            half8 bh = *(const half8*)&SB[B0H_OFF + idx0(0, kt, n16, q * 8)];
            half8 bl = *(const half8*)&SB[B0L_OFF + idx0(0, kt, n16, q * 8)];
            #pragma unroll
            for (int l = 0; l < 4; ++l) {
                acc[l] = __builtin_amdgcn_mfma_f32_16x16x32_f16(a0h[l][kt], bh, acc[l], 0, 0, 0);
                acc[l] = __builtin_amdgcn_mfma_f32_16x16x32_f16(a0l[l][kt], bh, acc[l], 0, 0, 0);
                acc[l] = __builtin_amdgcn_mfma_f32_16x16x32_f16(a0h[l][kt], bl, acc[l], 0, 0, 0);
            }
        }
        half4v hh, hl;
        cell_update(acc, c0r, hh, hl, nullptr);
        *(half4v*)&SB[B0H_OFF + idx0(1, ktw0, n16, kk)] = hh;
        *(half4v*)&SB[B0L_OFF + idx0(1, ktw0, n16, kk)] = hl;
        *(half4v*)&SB[B1H_OFF + idx1(1, ktw1, n16, kk)] = hh;
        *(half4v*)&SB[B1L_OFF + idx1(1, ktw1, n16, kk)] = hl;
    }
    __syncthreads();

    // x prefetch pointer: iteration t stages x(t+2)
    const float* xp = xp0 + 2 * DIN;

    // ---------------- main loop: ONE barrier per step ----------------
    // region R(t): L1(t)  ||  L0(t+1)  ||  stage x(t+2)
    #pragma unroll 2
    for (int t = 0; t < T - 1; ++t) {
        const int p = t & 1, pn = p ^ 1;

        // global prefetch x(t+2) (consumed at region end)
        float2 xv;
        const bool havex = (t < T - 2);
        if (havex) xv = *(const float2*)xp;
        xp += DIN;

        // ---- stream A: L1(t) MFMAs  (h0 fresh @ pn, h1 old @ p) ----
        float4v acc1[4];
        #pragma unroll
        for (int l = 0; l < 4; ++l) acc1[l] = bias1v[l];
        #pragma unroll
        for (int kt = 0; kt < 4; ++kt) {
            const int pp = (kt < 2) ? pn : p;
            half8 bh = *(const half8*)&SB[B1H_OFF + idx1(pp, kt, n16, q * 8)];
            half8 bl = *(const half8*)&SB[B1L_OFF + idx1(pp, kt, n16, q * 8)];
            #pragma unroll
            for (int l = 0; l < 4; ++l) {
                acc1[l] = __builtin_amdgcn_mfma_f32_16x16x32_f16(a1h[l][kt], bh, acc1[l], 0, 0, 0);
                acc1[l] = __builtin_amdgcn_mfma_f32_16x16x32_f16(a1l[l][kt], bh, acc1[l], 0, 0, 0);
                acc1[l] = __builtin_amdgcn_mfma_f32_16x16x32_f16(a1h[l][kt], bl, acc1[l], 0, 0, 0);
            }
        }

        // ---- stream B: L0(t+1) MFMAs  (x @ pn, h0 @ pn) ----
        float4v acc0[4];
        #pragma unroll
        for (int l = 0; l < 4; ++l) acc0[l] = bias0v[l];
        #pragma unroll
        for (int kt = 0; kt < 3; ++kt) {
            half8 bh = *(const half8*)&SB[B0H_OFF + idx0(pn, kt, n16, q * 8)];
            half8 bl = *(const half8*)&SB[B0L_OFF + idx0(pn, kt, n16, q * 8)];
            #pragma unroll
            for (int l = 0; l < 4; ++l) {
                acc0[l] = __builtin_amdgcn_mfma_f32_16x16x32_f16(a0h[l][kt], bh, acc0[l], 0, 0, 0);
                acc0[l] = __builtin_amdgcn_mfma_f32_16x16x32_f16(a0l[l][kt], bh, acc0[l], 0, 0, 0);
                acc0[l] = __builtin_amdgcn_mfma_f32_16x16x32_f16(a0h[l][kt], bl, acc0[l], 0, 0, 0);
            }
        }

        // ---- activations (two independent chains) ----
        half4v hh1, hl1, hh0, hl0;
        cell_update(acc1, c1r, hh1, hl1, nullptr);
        cell_update(acc0, c0r, hh0, hl0, nullptr);

        // ---- LDS writes ----
        // L1(t): h1 -> parity pn
        *(half4v*)&SB[B1H_OFF + idx1(pn, 2 + ktw1, n16, kk)] = hh1;
        *(half4v*)&SB[B1L_OFF + idx1(pn, 2 + ktw1, n16, kk)] = hl1;
        // L0(t+1): h0 -> parity p  ( = parity of t+2 )
        *(half4v*)&SB[B0H_OFF + idx0(p, ktw0, n16, kk)] = hh0;
        *(half4v*)&SB[B0L_OFF + idx0(p, ktw0, n16, kk)] = hl0;
        *(half4v*)&SB[B1H_OFF + idx1(p, ktw1, n16, kk)] = hh0;
        *(half4v*)&SB[B1L_OFF + idx1(p, ktw1, n16, kk)] = hl0;
        // stage x(t+2) -> parity p
        if (havex) {
            _Float16 hx0 = (_Float16)xv.x, hx1 = (_Float16)xv.y;
            half2v hi = {hx0, hx1};
            half2v lo = {(_Float16)(xv.x - (float)hx0), (_Float16)(xv.y - (float)hx1)};
            *(half2v*)&SB[B0H_OFF + idx0(p, 0, nx, kp)] = hi;
            *(half2v*)&SB[B0L_OFF + idx0(p, 0, nx, kp)] = lo;
        }
        __syncthreads();
    }

    // ---------------- final L1(T-1): p = 1 ----------------
    {
        const int p = (T - 1) & 1, pn = p ^ 1;
        float4v acc[4];
        #pragma unroll
        for (int l = 0; l < 4; ++l) acc[l] = bias1v[l];
        #pragma unroll
        for (int kt = 0; kt < 4; ++kt) {
            const int pp = (kt < 2) ? pn : p;
            half8 bh = *(const half8*)&SB[B1H_OFF + idx1(pp, kt, n16, q * 8)];
            half8 bl = *(const half8*)&SB[B1L_OFF + idx1(pp, kt, n16, q * 8)];
            #pragma unroll
            for (int l = 0; l < 4; ++l) {
                acc[l] = __builtin_amdgcn_mfma_f32_16x16x32_f16(a1h[l][kt], bh, acc[l], 0, 0, 0);
                acc[l] = __builtin_amdgcn_mfma_f32_16x16x32_f16(a1l[l][kt], bh, acc[l], 0, 0, 0);
                acc[l] = __builtin_amdgcn_mfma_f32_16x16x32_f16(a1h[l][kt], bl, acc[l], 0, 0, 0);
            }
        }
        half4v hh, hl;
        cell_update(acc, c1r, hh, hl, hlast);
    }

    // ---------------- head ----------------
    float* h1f = HS;             // [16][68]
    float* hid = HS + 16 * 68;   // [16][33]
    *(float4*)&h1f[n16 * 68 + j0] = *(const float4*)hlast;
    __syncthreads();

    {
        const int n2 = tid >> 4, m = tid & 15;
        float s0 = b1[m], s1 = b1[m + 16];
        const float* w0p = W1 + m * HCELLS;
        const float* w1p = W1 + (m + 16) * HCELLS;
        #pragma unroll
        for (int j = 0; j < HCELLS; ++j) {
            float hv = h1f[n2 * 68 + j];
            s0 = fmaf(w0p[j], hv, s0);
            s1 = fmaf(w1p[j], hv, s1);
        }
        hid[n2 * 33 + m]      = fmaxf(s0, 0.0f);
        hid[n2 * 33 + m + 16] = fmaxf(s1, 0.0f);
    }
    __syncthreads();

    if (tid < NB) {
        float s = b2[0];
        #pragma unroll
        for (int m = 0; m < 32; ++m) s = fmaf(W2[m], hid[tid * 33 + m], s);
        out[b0 + tid] = s;
    }
}

extern "C" void kernel_launch(void* const* d_in, const int* in_sizes, int n_in,
                              void* d_out, int out_size, void* d_ws, size_t ws_size,
                              hipStream_t stream) {
    const float* x    = (const float*)d_in[0];
    const float* Wih0 = (const float*)d_in[1];
    const float* Whh0 = (const float*)d_in[2];
    const float* bih0 = (const float*)d_in[3];
    const float* bhh0 = (const float*)d_in[4];
    const float* Wih1 = (const float*)d_in[5];
    const float* Whh1 = (const float*)d_in[6];
    const float* bih1 = (const float*)d_in[7];
    const float* bhh1 = (const float*)d_in[8];
    const float* W1   = (const float*)d_in[9];
    const float* b1   = (const float*)d_in[10];
    const float* W2   = (const float*)d_in[11];
    const float* b2   = (const float*)d_in[12];
    float* out = (float*)d_out;

    hipLaunchKernelGGL(lstm2_mfma_kernel, dim3(GRID), dim3(TB), 0, stream,
                       x, Wih0, Whh0, bih0, bhh0, Wih1, Whh1, bih1, bhh1,
                       W1, b1, W2, b2, out);
}

// Round 4
// 880.149 us; speedup vs baseline: 1.2420x; 1.2420x over previous
//
#include <hip/hip_runtime.h>

#define T       512
#define DIN     32
#define HCELLS  64
#define NB      16      // batch elems per block (MFMA N dim)
#define TB      256     // 4 waves
#define GRID    64      // 1024 / NB

typedef _Float16 half8  __attribute__((ext_vector_type(8)));
typedef _Float16 half4v __attribute__((ext_vector_type(4)));
typedef _Float16 half2v __attribute__((ext_vector_type(2)));
typedef float    float4v __attribute__((ext_vector_type(4)));

// LDS B-operand buffers (fp16). STRIDE=56 halves = 28 dwords per n-row:
// reads hit bank -4n+4q, writes -4n+2q+8(w&1) -> worst case 2-way (free).
#define STRIDE  56
#define B0H_OFF 0                           // [2][3][16][56]  x | h0(lo) | h0(hi)
#define B0L_OFF (2*3*16*STRIDE)
#define B1H_OFF (B0L_OFF + 2*3*16*STRIDE)   // [2][2][16][56]  h1 only
#define B1L_OFF (B1H_OFF + 2*2*16*STRIDE)
#define SB_HALFS (B1L_OFF + 2*2*16*STRIDE)

#define LOG2E   1.44269504f
#define SLOG2E  2.88539008f     // 2*log2(e); state is cs = SLOG2E * c

__device__ __forceinline__ int idx0(int p, int kt, int n, int k) {
    return ((p * 3 + kt) * 16 + n) * STRIDE + k;
}
__device__ __forceinline__ int idx1(int p, int kt, int n, int k) {
    return ((p * 2 + kt) * 16 + n) * STRIDE + k;
}

// split fp32 -> (hi, lo) fp16 pair
__device__ __forceinline__ void split8(const float* v, half8& hi, half8& lo) {
    #pragma unroll
    for (int e = 0; e < 8; ++e) {
        _Float16 h = (_Float16)v[e];
        hi[e] = h;
        lo[e] = (_Float16)(v[e] - (float)h);
    }
}

// Scaled-domain LSTM cell update. acc holds pre-scaled gate args:
//   acc[0] = -log2e*zi, acc[1] = -log2e*zf, acc[2] = 2log2e*zg, acc[3] = -log2e*zo
// State cs = 2log2e*c. 5 v_exp + 2 v_rcp per element, no argument muls.
__device__ __forceinline__ void cell_update(const float4v acc[4], float* cs,
                                            half4v& hh, half4v& hl, float* hout)
{
    #pragma unroll
    for (int r = 0; r < 4; ++r) {
        float ei = __builtin_amdgcn_exp2f(acc[0][r]);   // e^{-zi}
        float ef = __builtin_amdgcn_exp2f(acc[1][r]);   // e^{-zf}
        float G2 = __builtin_amdgcn_exp2f(acc[2][r]);   // e^{2 zg}
        float I  = 1.0f + ei, F = 1.0f + ef;
        float Gp = 1.0f + G2;
        float Gms = fmaf(SLOG2E, G2, -SLOG2E);          // s*(G2-1)
        float P   = I * Gp;
        float num = fmaf(F, Gms, cs[r] * P);
        float csn = num * __builtin_amdgcn_rcpf(F * P);
        csn = fminf(fmaxf(csn, -50.0f), 50.0f);         // c' in +-17.3, tanh saturated
        cs[r] = csn;
        float eo = __builtin_amdgcn_exp2f(acc[3][r]);   // e^{-zo}
        float C2 = __builtin_amdgcn_exp2f(csn);         // e^{2 c'}
        float O  = 1.0f + eo;
        float Cp = 1.0f + C2, Cm = C2 - 1.0f;
        float h  = Cm * __builtin_amdgcn_rcpf(O * Cp);
        if (hout) hout[r] = h;
        _Float16 h16 = (_Float16)h;
        hh[r] = h16;
        hl[r] = (_Float16)(h - (float)h16);
    }
}

__global__ void __launch_bounds__(TB, 1)
lstm2_mfma_kernel(const float* __restrict__ x,
                  const float* __restrict__ Wih0, const float* __restrict__ Whh0,
                  const float* __restrict__ bih0, const float* __restrict__ bhh0,
                  const float* __restrict__ Wih1, const float* __restrict__ Whh1,
                  const float* __restrict__ bih1, const float* __restrict__ bhh1,
                  const float* __restrict__ W1,   const float* __restrict__ b1,
                  const float* __restrict__ W2,   const float* __restrict__ b2,
                  float* __restrict__ out)
{
    const int tid  = threadIdx.x;
    const int w    = tid >> 6;          // wave 0..3
    const int lane = tid & 63;
    const int n16  = lane & 15;         // MFMA free-index / local batch
    const int q    = lane >> 4;         // quad 0..3
    const int j0   = w * 16 + q * 4;    // this thread's hidden-unit base (4 rows)
    const int b0   = blockIdx.x * NB;   // global batch base

    __shared__ __align__(16) _Float16 SB[SB_HALFS];
    __shared__ __align__(16) float HS[16 * 68 + 16 * 33];  // head scratch

    // per-gate scale folded into weights+biases (l = gate index i,f,g,o)
    const float gsc[4] = {-LOG2E, -LOG2E, SLOG2E, -LOG2E};

    // ---------------- A-fragments (weights, hi/lo fp16) in registers ----------------
    half8 a0h[4][3], a0l[4][3];   // layer0: K = 96 (x 32 | h0 64)
    half8 a1h[4][4], a1l[4][4];   // layer1: K = 128 (h0 64 | h1 64)
    float4v bias0v[4], bias1v[4];

    #pragma unroll
    for (int l = 0; l < 4; ++l) {
        const int row = (l * 4 + w) * 16 + n16;
        const float g = gsc[l];
        float v[8];
        {
            const float4* p = (const float4*)(Wih0 + row * DIN + q * 8);
            float4 u0 = p[0], u1 = p[1];
            v[0]=g*u0.x; v[1]=g*u0.y; v[2]=g*u0.z; v[3]=g*u0.w;
            v[4]=g*u1.x; v[5]=g*u1.y; v[6]=g*u1.z; v[7]=g*u1.w;
            split8(v, a0h[l][0], a0l[l][0]);
        }
        #pragma unroll
        for (int kt = 1; kt < 3; ++kt) {
            const float4* p = (const float4*)(Whh0 + row * HCELLS + (kt - 1) * 32 + q * 8);
            float4 u0 = p[0], u1 = p[1];
            v[0]=g*u0.x; v[1]=g*u0.y; v[2]=g*u0.z; v[3]=g*u0.w;
            v[4]=g*u1.x; v[5]=g*u1.y; v[6]=g*u1.z; v[7]=g*u1.w;
            split8(v, a0h[l][kt], a0l[l][kt]);
        }
        #pragma unroll
        for (int kt = 0; kt < 4; ++kt) {
            const float* base = (kt < 2) ? (Wih1 + row * HCELLS + kt * 32)
                                         : (Whh1 + row * HCELLS + (kt - 2) * 32);
            const float4* p = (const float4*)(base + q * 8);
            float4 u0 = p[0], u1 = p[1];
            v[0]=g*u0.x; v[1]=g*u0.y; v[2]=g*u0.z; v[3]=g*u0.w;
            v[4]=g*u1.x; v[5]=g*u1.y; v[6]=g*u1.z; v[7]=g*u1.w;
            split8(v, a1h[l][kt], a1l[l][kt]);
        }
        const int r0 = l * 64 + j0;
        float4v bi = *(const float4v*)(bih0 + r0);
        float4v bh = *(const float4v*)(bhh0 + r0);
        bias0v[l] = (bi + bh) * g;
        bi = *(const float4v*)(bih1 + r0);
        bh = *(const float4v*)(bhh1 + r0);
        bias1v[l] = (bi + bh) * g;
    }

    // ---------------- zero LDS, stage x(0) at parity 0 ----------------
    for (int i = tid; i < SB_HALFS / 2; i += TB) ((int*)SB)[i] = 0;

    const int nx = tid >> 4;            // x-loader: batch 0..15
    const int kp = (tid & 15) * 2;      // x-loader: k pair 0..30
    const float* xp0 = x + (size_t)(b0 + nx) * T * DIN + kp;
    __syncthreads();
    {
        float2 xv = *(const float2*)xp0;
        _Float16 hx0 = (_Float16)xv.x, hx1 = (_Float16)xv.y;
        half2v hi = {hx0, hx1};
        half2v lo = {(_Float16)(xv.x - (float)hx0), (_Float16)(xv.y - (float)hx1)};
        *(half2v*)&SB[B0H_OFF + idx0(0, 0, nx, kp)] = hi;
        *(half2v*)&SB[B0L_OFF + idx0(0, 0, nx, kp)] = lo;
    }
    __syncthreads();

    float cs0[4] = {0, 0, 0, 0}, cs1[4] = {0, 0, 0, 0};
    float hlast[4];

    const int ktw0 = 1 + (j0 >> 5);     // h0 slot in B0 (k = 32 + j)
    const int ktw1 = (j0 >> 5);         // h1 slot in B1
    const int kk   = j0 & 31;

    // x prefetch pointer: iteration t loads x(t+1)
    const float* xp = xp0 + DIN;

    // ---------------- time loop: 2 barriers/step (round-2 skeleton) ----------------
    #pragma unroll 2
    for (int t = 0; t < T; ++t) {
        const int cur = t & 1, nxt = cur ^ 1;

        // prefetch x(t+1): issued at step top, consumed before the 2nd barrier
        float2 xv;
        const bool havex = (t + 1 < T);
        if (havex) xv = *(const float2*)xp;
        xp += DIN;

        // ---- phase 1: L0(t)  reads x(t)@cur, h0(t-1)@cur (B0) ----
        float4v acc0[4];
        #pragma unroll
        for (int l = 0; l < 4; ++l) acc0[l] = bias0v[l];
        #pragma unroll
        for (int kt = 0; kt < 3; ++kt) {
            half8 bh = *(const half8*)&SB[B0H_OFF + idx0(cur, kt, n16, q * 8)];
            half8 bl = *(const half8*)&SB[B0L_OFF + idx0(cur, kt, n16, q * 8)];
            #pragma unroll
            for (int l = 0; l < 4; ++l) {
                acc0[l] = __builtin_amdgcn_mfma_f32_16x16x32_f16(a0h[l][kt], bh, acc0[l], 0, 0, 0);
                acc0[l] = __builtin_amdgcn_mfma_f32_16x16x32_f16(a0l[l][kt], bh, acc0[l], 0, 0, 0);
                acc0[l] = __builtin_amdgcn_mfma_f32_16x16x32_f16(a0h[l][kt], bl, acc0[l], 0, 0, 0);
            }
        }
        {
            half4v hh, hl;
            cell_update(acc0, cs0, hh, hl, nullptr);
            // h0(t) -> B0 @nxt only (L1 reads it from B0 slots 1,2 directly)
            *(half4v*)&SB[B0H_OFF + idx0(nxt, ktw0, n16, kk)] = hh;
            *(half4v*)&SB[B0L_OFF + idx0(nxt, ktw0, n16, kk)] = hl;
        }
        __syncthreads();   // h0(t) visible

        // ---- phase 2: L1(t)  reads h0(t)@nxt (B0 slots 1,2), h1(t-1)@cur (B1) ----
        float4v acc1[4];
        #pragma unroll
        for (int l = 0; l < 4; ++l) acc1[l] = bias1v[l];
        #pragma unroll
        for (int kt = 0; kt < 4; ++kt) {
            half8 bh, bl;
            if (kt < 2) {
                bh = *(const half8*)&SB[B0H_OFF + idx0(nxt, kt + 1, n16, q * 8)];
                bl = *(const half8*)&SB[B0L_OFF + idx0(nxt, kt + 1, n16, q * 8)];
            } else {
                bh = *(const half8*)&SB[B1H_OFF + idx1(cur, kt - 2, n16, q * 8)];
                bl = *(const half8*)&SB[B1L_OFF + idx1(cur, kt - 2, n16, q * 8)];
            }
            #pragma unroll
            for (int l = 0; l < 4; ++l) {
                acc1[l] = __builtin_amdgcn_mfma_f32_16x16x32_f16(a1h[l][kt], bh, acc1[l], 0, 0, 0);
                acc1[l] = __builtin_amdgcn_mfma_f32_16x16x32_f16(a1l[l][kt], bh, acc1[l], 0, 0, 0);
                acc1[l] = __builtin_amdgcn_mfma_f32_16x16x32_f16(a1h[l][kt], bl, acc1[l], 0, 0, 0);
            }
        }
        {
            half4v hh, hl;
            cell_update(acc1, cs1, hh, hl, hlast);
            *(half4v*)&SB[B1H_OFF + idx1(nxt, ktw1, n16, kk)] = hh;
            *(half4v*)&SB[B1L_OFF + idx1(nxt, ktw1, n16, kk)] = hl;
        }
        // stage x(t+1) -> @nxt
        if (havex) {
            _Float16 hx0 = (_Float16)xv.x, hx1 = (_Float16)xv.y;
            half2v hi = {hx0, hx1};
            half2v lo = {(_Float16)(xv.x - (float)hx0), (_Float16)(xv.y - (float)hx1)};
            *(half2v*)&SB[B0H_OFF + idx0(nxt, 0, nx, kp)] = hi;
            *(half2v*)&SB[B0L_OFF + idx0(nxt, 0, nx, kp)] = lo;
        }
        __syncthreads();
    }

    // ---------------- head: relu(h1 @ W1^T + b1) @ W2^T + b2 ----------------
    float* h1f = HS;             // [16][68]
    float* hid = HS + 16 * 68;   // [16][33]
    *(float4*)&h1f[n16 * 68 + j0] = *(const float4*)hlast;
    __syncthreads();

    {
        const int n2 = tid >> 4, m = tid & 15;
        float s0 = b1[m], s1 = b1[m + 16];
        const float* w0p = W1 + m * HCELLS;
        const float* w1p = W1 + (m + 16) * HCELLS;
        #pragma unroll
        for (int j = 0; j < HCELLS; ++j) {
            float hv = h1f[n2 * 68 + j];
            s0 = fmaf(w0p[j], hv, s0);
            s1 = fmaf(w1p[j], hv, s1);
        }
        hid[n2 * 33 + m]      = fmaxf(s0, 0.0f);
        hid[n2 * 33 + m + 16] = fmaxf(s1, 0.0f);
    }
    __syncthreads();

    if (tid < NB) {
        float s = b2[0];
        #pragma unroll
        for (int m = 0; m < 32; ++m) s = fmaf(W2[m], hid[tid * 33 + m], s);
        out[b0 + tid] = s;
    }
}

extern "C" void kernel_launch(void* const* d_in, const int* in_sizes, int n_in,
                              void* d_out, int out_size, void* d_ws, size_t ws_size,
                              hipStream_t stream) {
    const float* x    = (const float*)d_in[0];
    const float* Wih0 = (const float*)d_in[1];
    const float* Whh0 = (const float*)d_in[2];
    const float* bih0 = (const float*)d_in[3];
    const float* bhh0 = (const float*)d_in[4];
    const float* Wih1 = (const float*)d_in[5];
    const float* Whh1 = (const float*)d_in[6];
    const float* bih1 = (const float*)d_in[7];
    const float* bhh1 = (const float*)d_in[8];
    const float* W1   = (const float*)d_in[9];
    const float* b1   = (const float*)d_in[10];
    const float* W2   = (const float*)d_in[11];
    const float* b2   = (const float*)d_in[12];
    float* out = (float*)d_out;

    hipLaunchKernelGGL(lstm2_mfma_kernel, dim3(GRID), dim3(TB), 0, stream,
                       x, Wih0, Whh0, bih0, bhh0, Wih1, Whh1, bih1, bhh1,
                       W1, b1, W2, b2, out);
}

// Round 5
// 639.929 us; speedup vs baseline: 1.7082x; 1.3754x over previous
//
#include <hip/hip_runtime.h>

#define T       512
#define DIN     32
#define HCELLS  64
#define NB      16      // batch elems per block (MFMA N dim)
#define TB      512     // 8 waves: group A = waves 0-3 (layer 0), group B = waves 4-7 (layer 1)
#define GRID    64      // 1024 / NB

typedef _Float16 half8  __attribute__((ext_vector_type(8)));
typedef _Float16 half4v __attribute__((ext_vector_type(4)));
typedef _Float16 half2v __attribute__((ext_vector_type(2)));
typedef float    float4v __attribute__((ext_vector_type(4)));

// LDS fp16 buffers, one flat array. Strides in halves.
#define STRX    40      // x rows: 32 + 8 pad
#define STRH    72      // h rows: 64 + 8 pad
#define XH_OFF  0                       // [2][16][STRX]
#define XL_OFF  (2*16*STRX)
#define H0H_OFF (XL_OFF + 2*16*STRX)    // [2][16][STRH]
#define H0L_OFF (H0H_OFF + 2*16*STRH)
#define H1H_OFF (H0L_OFF + 2*16*STRH)
#define H1L_OFF (H1H_OFF + 2*16*STRH)
#define SB_HALFS (H1L_OFF + 2*16*STRH)

#define LOG2E   1.44269504f
#define SLOG2E  2.88539008f     // 2*log2(e); cell state kept as cs = SLOG2E * c

__device__ __forceinline__ int xidx(int p, int n, int k) { return (p * 16 + n) * STRX + k; }
__device__ __forceinline__ int hidx(int p, int n, int k) { return (p * 16 + n) * STRH + k; }

// split fp32 -> (hi, lo) fp16 pair
__device__ __forceinline__ void split8(const float* v, half8& hi, half8& lo) {
    #pragma unroll
    for (int e = 0; e < 8; ++e) {
        _Float16 h = (_Float16)v[e];
        hi[e] = h;
        lo[e] = (_Float16)(v[e] - (float)h);
    }
}

// Scaled-domain LSTM cell update (gate args pre-scaled by +-log2e folded into weights):
//   acc[0]=-log2e*zi, acc[1]=-log2e*zf, acc[2]=2log2e*zg, acc[3]=-log2e*zo ; cs = 2log2e*c
__device__ __forceinline__ void cell_update(const float4v acc[4], float* cs,
                                            half4v& hh, half4v& hl, float* hout)
{
    #pragma unroll
    for (int r = 0; r < 4; ++r) {
        float ei = __builtin_amdgcn_exp2f(acc[0][r]);   // e^{-zi}
        float ef = __builtin_amdgcn_exp2f(acc[1][r]);   // e^{-zf}
        float G2 = __builtin_amdgcn_exp2f(acc[2][r]);   // e^{2 zg}
        float I  = 1.0f + ei, F = 1.0f + ef;
        float Gp = 1.0f + G2;
        float Gms = fmaf(SLOG2E, G2, -SLOG2E);          // s*(G2-1)
        float P   = I * Gp;
        float num = fmaf(F, Gms, cs[r] * P);
        float csn = num * __builtin_amdgcn_rcpf(F * P);
        csn = fminf(fmaxf(csn, -50.0f), 50.0f);
        cs[r] = csn;
        float eo = __builtin_amdgcn_exp2f(acc[3][r]);   // e^{-zo}
        float C2 = __builtin_amdgcn_exp2f(csn);         // e^{2 c'}
        float O  = 1.0f + eo;
        float Cp = 1.0f + C2, Cm = C2 - 1.0f;
        float h  = Cm * __builtin_amdgcn_rcpf(O * Cp);
        if (hout) hout[r] = h;
        _Float16 h16 = (_Float16)h;
        hh[r] = h16;
        hl[r] = (_Float16)(h - (float)h16);
    }
}

__global__ void __launch_bounds__(TB, 2)
lstm2_mfma_kernel(const float* __restrict__ x,
                  const float* __restrict__ Wih0, const float* __restrict__ Whh0,
                  const float* __restrict__ bih0, const float* __restrict__ bhh0,
                  const float* __restrict__ Wih1, const float* __restrict__ Whh1,
                  const float* __restrict__ bih1, const float* __restrict__ bhh1,
                  const float* __restrict__ W1,   const float* __restrict__ b1,
                  const float* __restrict__ W2,   const float* __restrict__ b2,
                  float* __restrict__ out)
{
    const int tid  = threadIdx.x;
    const int wid  = tid >> 6;
    const int grp  = wid >> 2;          // 0 = layer-0 group, 1 = layer-1 group
    const int wl   = wid & 3;           // local wave in group
    const int lane = tid & 63;
    const int n16  = lane & 15;         // MFMA free index / local batch
    const int q    = lane >> 4;         // quad 0..3
    const int j0   = wl * 16 + q * 4;   // this thread's hidden-unit base (4 rows)
    const int b0   = blockIdx.x * NB;

    __shared__ __align__(16) _Float16 SB[SB_HALFS];
    __shared__ __align__(16) float HS[16 * 68 + 16 * 33];

    const float gsc[4] = {-LOG2E, -LOG2E, SLOG2E, -LOG2E};

    // ---------------- per-group weight fragments (hi/lo fp16) ----------------
    // grp0 uses kt 0..2 (K=96: x32|h0 64); grp1 uses kt 0..3 (K=128: h0 64|h1 64)
    half8 ah[4][4], al[4][4];
    float4v biasv[4];

    #pragma unroll
    for (int l = 0; l < 4; ++l) {
        const int row = (l * 4 + wl) * 16 + n16;
        const float g = gsc[l];
        float v[8];
        if (grp == 0) {
            {
                const float4* p = (const float4*)(Wih0 + row * DIN + q * 8);
                float4 u0 = p[0], u1 = p[1];
                v[0]=g*u0.x; v[1]=g*u0.y; v[2]=g*u0.z; v[3]=g*u0.w;
                v[4]=g*u1.x; v[5]=g*u1.y; v[6]=g*u1.z; v[7]=g*u1.w;
                split8(v, ah[l][0], al[l][0]);
            }
            #pragma unroll
            for (int kt = 1; kt < 3; ++kt) {
                const float4* p = (const float4*)(Whh0 + row * HCELLS + (kt - 1) * 32 + q * 8);
                float4 u0 = p[0], u1 = p[1];
                v[0]=g*u0.x; v[1]=g*u0.y; v[2]=g*u0.z; v[3]=g*u0.w;
                v[4]=g*u1.x; v[5]=g*u1.y; v[6]=g*u1.z; v[7]=g*u1.w;
                split8(v, ah[l][kt], al[l][kt]);
            }
            const int r0 = l * 64 + j0;
            float4v bi = *(const float4v*)(bih0 + r0);
            float4v bh = *(const float4v*)(bhh0 + r0);
            biasv[l] = (bi + bh) * g;
        } else {
            #pragma unroll
            for (int kt = 0; kt < 4; ++kt) {
                const float* base = (kt < 2) ? (Wih1 + row * HCELLS + kt * 32)
                                             : (Whh1 + row * HCELLS + (kt - 2) * 32);
                const float4* p = (const float4*)(base + q * 8);
                float4 u0 = p[0], u1 = p[1];
                v[0]=g*u0.x; v[1]=g*u0.y; v[2]=g*u0.z; v[3]=g*u0.w;
                v[4]=g*u1.x; v[5]=g*u1.y; v[6]=g*u1.z; v[7]=g*u1.w;
                split8(v, ah[l][kt], al[l][kt]);
            }
            const int r0 = l * 64 + j0;
            float4v bi = *(const float4v*)(bih1 + r0);
            float4v bh = *(const float4v*)(bhh1 + r0);
            biasv[l] = (bi + bh) * g;
        }
    }

    // ---------------- zero LDS, stage x(0) -> slot 0 ----------------
    for (int i = tid; i < SB_HALFS / 2; i += TB) ((int*)SB)[i] = 0;

    const int nx = tid >> 4;            // x-loader role (grp0 threads: tid<256)
    const int kp = (tid & 15) * 2;
    const float* xp0 = (grp == 0) ? (x + (size_t)(b0 + nx) * T * DIN + kp) : nullptr;
    __syncthreads();
    if (grp == 0) {
        float2 xv = *(const float2*)xp0;
        _Float16 hx0 = (_Float16)xv.x, hx1 = (_Float16)xv.y;
        half2v hi = {hx0, hx1};
        half2v lo = {(_Float16)(xv.x - (float)hx0), (_Float16)(xv.y - (float)hx1)};
        *(half2v*)&SB[XH_OFF + xidx(0, nx, kp)] = hi;
        *(half2v*)&SB[XL_OFF + xidx(0, nx, kp)] = lo;
    }
    __syncthreads();

    float cs[4] = {0, 0, 0, 0};
    float hlast[4];
    const float* xp = (grp == 0) ? (xp0 + DIN) : nullptr;

    // ---------------- pipelined time loop: ONE barrier per region ----------------
    // region t: A computes L0(t); B computes L1(t-1) (t>=1)
    // slots: v(tau) lives in slot (tau+1)&1
    #pragma unroll 2
    for (int t = 0; t < T; ++t) {
        const int pr = t & 1, pw = pr ^ 1;

        if (grp == 0) {
            // prefetch x(t+1)
            float2 xv;
            const bool havex = (t + 1 < T);
            if (havex) xv = *(const float2*)xp;
            xp += DIN;

            float4v acc[4];
            #pragma unroll
            for (int l = 0; l < 4; ++l) acc[l] = biasv[l];
            // kt=0: x(t) @ X[pr]
            {
                half8 bh = *(const half8*)&SB[XH_OFF + xidx(pr, n16, q * 8)];
                half8 bl = *(const half8*)&SB[XL_OFF + xidx(pr, n16, q * 8)];
                #pragma unroll
                for (int l = 0; l < 4; ++l) {
                    acc[l] = __builtin_amdgcn_mfma_f32_16x16x32_f16(ah[l][0], bh, acc[l], 0, 0, 0);
                    acc[l] = __builtin_amdgcn_mfma_f32_16x16x32_f16(al[l][0], bh, acc[l], 0, 0, 0);
                    acc[l] = __builtin_amdgcn_mfma_f32_16x16x32_f16(ah[l][0], bl, acc[l], 0, 0, 0);
                }
            }
            // kt=1,2: h0(t-1) @ H0[pr]
            #pragma unroll
            for (int kt = 1; kt < 3; ++kt) {
                half8 bh = *(const half8*)&SB[H0H_OFF + hidx(pr, n16, (kt - 1) * 32 + q * 8)];
                half8 bl = *(const half8*)&SB[H0L_OFF + hidx(pr, n16, (kt - 1) * 32 + q * 8)];
                #pragma unroll
                for (int l = 0; l < 4; ++l) {
                    acc[l] = __builtin_amdgcn_mfma_f32_16x16x32_f16(ah[l][kt], bh, acc[l], 0, 0, 0);
                    acc[l] = __builtin_amdgcn_mfma_f32_16x16x32_f16(al[l][kt], bh, acc[l], 0, 0, 0);
                    acc[l] = __builtin_amdgcn_mfma_f32_16x16x32_f16(ah[l][kt], bl, acc[l], 0, 0, 0);
                }
            }
            half4v hh, hl;
            cell_update(acc, cs, hh, hl, nullptr);
            *(half4v*)&SB[H0H_OFF + hidx(pw, n16, j0)] = hh;   // h0(t) -> slot pw
            *(half4v*)&SB[H0L_OFF + hidx(pw, n16, j0)] = hl;
            // stage x(t+1) -> X[pw]
            if (havex) {
                _Float16 hx0 = (_Float16)xv.x, hx1 = (_Float16)xv.y;
                half2v hi = {hx0, hx1};
                half2v lo = {(_Float16)(xv.x - (float)hx0), (_Float16)(xv.y - (float)hx1)};
                *(half2v*)&SB[XH_OFF + xidx(pw, nx, kp)] = hi;
                *(half2v*)&SB[XL_OFF + xidx(pw, nx, kp)] = lo;
            }
        } else if (t > 0) {
            // L1(t-1): h0(t-1) @ H0[pr], h1(t-2) @ H1[pw]
            float4v acc[4];
            #pragma unroll
            for (int l = 0; l < 4; ++l) acc[l] = biasv[l];
            #pragma unroll
            for (int kt = 0; kt < 4; ++kt) {
                half8 bh, bl;
                if (kt < 2) {
                    bh = *(const half8*)&SB[H0H_OFF + hidx(pr, n16, kt * 32 + q * 8)];
                    bl = *(const half8*)&SB[H0L_OFF + hidx(pr, n16, kt * 32 + q * 8)];
                } else {
                    bh = *(const half8*)&SB[H1H_OFF + hidx(pw, n16, (kt - 2) * 32 + q * 8)];
                    bl = *(const half8*)&SB[H1L_OFF + hidx(pw, n16, (kt - 2) * 32 + q * 8)];
                }
                #pragma unroll
                for (int l = 0; l < 4; ++l) {
                    acc[l] = __builtin_amdgcn_mfma_f32_16x16x32_f16(ah[l][kt], bh, acc[l], 0, 0, 0);
                    acc[l] = __builtin_amdgcn_mfma_f32_16x16x32_f16(al[l][kt], bh, acc[l], 0, 0, 0);
                    acc[l] = __builtin_amdgcn_mfma_f32_16x16x32_f16(ah[l][kt], bl, acc[l], 0, 0, 0);
                }
            }
            half4v hh, hl;
            cell_update(acc, cs, hh, hl, nullptr);
            *(half4v*)&SB[H1H_OFF + hidx(pr, n16, j0)] = hh;   // h1(t-1) -> slot pr
            *(half4v*)&SB[H1L_OFF + hidx(pr, n16, j0)] = hl;
        }
        __syncthreads();
    }

    // ---------------- epilogue: B computes L1(T-1) ----------------
    // h0(T-1) in slot T&1 = 0 ; h1(T-2) in slot (T-1)&1 = 1   (T even)
    float* h1f = HS;             // [16][68]
    float* hid = HS + 16 * 68;   // [16][33]
    if (grp == 1) {
        float4v acc[4];
        #pragma unroll
        for (int l = 0; l < 4; ++l) acc[l] = biasv[l];
        #pragma unroll
        for (int kt = 0; kt < 4; ++kt) {
            half8 bh, bl;
            if (kt < 2) {
                bh = *(const half8*)&SB[H0H_OFF + hidx(0, n16, kt * 32 + q * 8)];
                bl = *(const half8*)&SB[H0L_OFF + hidx(0, n16, kt * 32 + q * 8)];
            } else {
                bh = *(const half8*)&SB[H1H_OFF + hidx(1, n16, (kt - 2) * 32 + q * 8)];
                bl = *(const half8*)&SB[H1L_OFF + hidx(1, n16, (kt - 2) * 32 + q * 8)];
            }
            #pragma unroll
            for (int l = 0; l < 4; ++l) {
                acc[l] = __builtin_amdgcn_mfma_f32_16x16x32_f16(ah[l][kt], bh, acc[l], 0, 0, 0);
                acc[l] = __builtin_amdgcn_mfma_f32_16x16x32_f16(al[l][kt], bh, acc[l], 0, 0, 0);
                acc[l] = __builtin_amdgcn_mfma_f32_16x16x32_f16(ah[l][kt], bl, acc[l], 0, 0, 0);
            }
        }
        half4v hh, hl;
        cell_update(acc, cs, hh, hl, hlast);
        *(float4*)&h1f[n16 * 68 + j0] = *(const float4*)hlast;
    }
    __syncthreads();

    // ---------------- head: relu(h1 @ W1^T + b1) @ W2^T + b2 ----------------
    if (tid < 256) {
        const int n2 = tid >> 4, m = tid & 15;
        float s0 = b1[m], s1 = b1[m + 16];
        const float* w0p = W1 + m * HCELLS;
        const float* w1p = W1 + (m + 16) * HCELLS;
        #pragma unroll
        for (int j = 0; j < HCELLS; ++j) {
            float hv = h1f[n2 * 68 + j];
            s0 = fmaf(w0p[j], hv, s0);
            s1 = fmaf(w1p[j], hv, s1);
        }
        hid[n2 * 33 + m]      = fmaxf(s0, 0.0f);
        hid[n2 * 33 + m + 16] = fmaxf(s1, 0.0f);
    }
    __syncthreads();

    if (tid < NB) {
        float s = b2[0];
        #pragma unroll
        for (int m = 0; m < 32; ++m) s = fmaf(W2[m], hid[tid * 33 + m], s);
        out[b0 + tid] = s;
    }
}

extern "C" void kernel_launch(void* const* d_in, const int* in_sizes, int n_in,
                              void* d_out, int out_size, void* d_ws, size_t ws_size,
                              hipStream_t stream) {
    const float* x    = (const float*)d_in[0];
    const float* Wih0 = (const float*)d_in[1];
    const float* Whh0 = (const float*)d_in[2];
    const float* bih0 = (const float*)d_in[3];
    const float* bhh0 = (const float*)d_in[4];
    const float* Wih1 = (const float*)d_in[5];
    const float* Whh1 = (const float*)d_in[6];
    const float* bih1 = (const float*)d_in[7];
    const float* bhh1 = (const float*)d_in[8];
    const float* W1   = (const float*)d_in[9];
    const float* b1   = (const float*)d_in[10];
    const float* W2   = (const float*)d_in[11];
    const float* b2   = (const float*)d_in[12];
    float* out = (float*)d_out;

    hipLaunchKernelGGL(lstm2_mfma_kernel, dim3(GRID), dim3(TB), 0, stream,
                       x, Wih0, Whh0, bih0, bhh0, Wih1, Whh1, bih1, bhh1,
                       W1, b1, W2, b2, out);
}

// Round 6
// 529.068 us; speedup vs baseline: 2.0662x; 1.2095x over previous
//
#include <hip/hip_runtime.h>

#define T       512
#define DIN     32
#define HCELLS  64
#define NB      16      // batch elems per block (MFMA N dim)
#define TB      512     // 8 waves: group A = waves 0-3 (layer 0), group B = waves 4-7 (layer 1)
#define GRID    64      // 1024 / NB

typedef _Float16 half8  __attribute__((ext_vector_type(8)));
typedef _Float16 half4v __attribute__((ext_vector_type(4)));
typedef _Float16 half2v __attribute__((ext_vector_type(2)));
typedef float    float4v __attribute__((ext_vector_type(4)));

// LDS fp16 buffers (hi only -- B-operand lo correction dropped; A keeps hi/lo).
#define STRX    40      // x rows: 32 + 8 pad
#define STRH    72      // h rows: 64 + 8 pad
#define XH_OFF  0                       // [2][16][STRX]
#define H0H_OFF (2*16*STRX)             // [2][16][STRH]
#define H1H_OFF (H0H_OFF + 2*16*STRH)
#define SB_HALFS (H1H_OFF + 2*16*STRH)

#define LOG2E   1.44269504f
#define SLOG2E  2.88539008f     // 2*log2(e); cell state kept as cs = SLOG2E * c

__device__ __forceinline__ int xidx(int p, int n, int k) { return (p * 16 + n) * STRX + k; }
__device__ __forceinline__ int hidx(int p, int n, int k) { return (p * 16 + n) * STRH + k; }

// split fp32 -> (hi, lo) fp16 pair (weights only)
__device__ __forceinline__ void split8(const float* v, half8& hi, half8& lo) {
    #pragma unroll
    for (int e = 0; e < 8; ++e) {
        _Float16 h = (_Float16)v[e];
        hi[e] = h;
        lo[e] = (_Float16)(v[e] - (float)h);
    }
}

// Scaled-domain LSTM cell update (gate scales folded into weights):
//   acc[0]=-log2e*zi, acc[1]=-log2e*zf, acc[2]=2log2e*zg, acc[3]=-log2e*zo ; cs = 2log2e*c
__device__ __forceinline__ void cell_update(const float4v acc[4], float* cs,
                                            half4v& hh, float* hout)
{
    #pragma unroll
    for (int r = 0; r < 4; ++r) {
        float ei = __builtin_amdgcn_exp2f(acc[0][r]);   // e^{-zi}
        float ef = __builtin_amdgcn_exp2f(acc[1][r]);   // e^{-zf}
        float G2 = __builtin_amdgcn_exp2f(acc[2][r]);   // e^{2 zg}
        float I  = 1.0f + ei, F = 1.0f + ef;
        float Gp = 1.0f + G2;
        float Gms = fmaf(SLOG2E, G2, -SLOG2E);          // s*(G2-1)
        float P   = I * Gp;
        float num = fmaf(F, Gms, cs[r] * P);
        float csn = num * __builtin_amdgcn_rcpf(F * P);
        csn = fminf(fmaxf(csn, -50.0f), 50.0f);
        cs[r] = csn;
        float eo = __builtin_amdgcn_exp2f(acc[3][r]);   // e^{-zo}
        float C2 = __builtin_amdgcn_exp2f(csn);         // e^{2 c'}
        float O  = 1.0f + eo;
        float Cp = 1.0f + C2, Cm = C2 - 1.0f;
        float h  = Cm * __builtin_amdgcn_rcpf(O * Cp);
        if (hout) hout[r] = h;
        hh[r] = (_Float16)h;
    }
}

__global__ void __launch_bounds__(TB, 2)
lstm2_mfma_kernel(const float* __restrict__ x,
                  const float* __restrict__ Wih0, const float* __restrict__ Whh0,
                  const float* __restrict__ bih0, const float* __restrict__ bhh0,
                  const float* __restrict__ Wih1, const float* __restrict__ Whh1,
                  const float* __restrict__ bih1, const float* __restrict__ bhh1,
                  const float* __restrict__ W1,   const float* __restrict__ b1,
                  const float* __restrict__ W2,   const float* __restrict__ b2,
                  float* __restrict__ out)
{
    const int tid  = threadIdx.x;
    const int wid  = tid >> 6;
    const int grp  = wid >> 2;          // 0 = layer-0 group, 1 = layer-1 group
    const int wl   = wid & 3;           // local wave in group
    const int lane = tid & 63;
    const int n16  = lane & 15;         // MFMA free index / local batch
    const int q    = lane >> 4;         // quad 0..3
    const int j0   = wl * 16 + q * 4;   // this thread's hidden-unit base (4 rows)
    const int b0   = blockIdx.x * NB;

    __shared__ __align__(16) _Float16 SB[SB_HALFS];
    __shared__ __align__(16) float HS[16 * 68 + 16 * 33];

    const float gsc[4] = {-LOG2E, -LOG2E, SLOG2E, -LOG2E};

    // ---------------- per-group weight fragments (hi/lo fp16) ----------------
    half8 ah[4][4], al[4][4];
    float4v biasv[4];

    #pragma unroll
    for (int l = 0; l < 4; ++l) {
        const int row = (l * 4 + wl) * 16 + n16;
        const float g = gsc[l];
        float v[8];
        if (grp == 0) {
            {
                const float4* p = (const float4*)(Wih0 + row * DIN + q * 8);
                float4 u0 = p[0], u1 = p[1];
                v[0]=g*u0.x; v[1]=g*u0.y; v[2]=g*u0.z; v[3]=g*u0.w;
                v[4]=g*u1.x; v[5]=g*u1.y; v[6]=g*u1.z; v[7]=g*u1.w;
                split8(v, ah[l][0], al[l][0]);
            }
            #pragma unroll
            for (int kt = 1; kt < 3; ++kt) {
                const float4* p = (const float4*)(Whh0 + row * HCELLS + (kt - 1) * 32 + q * 8);
                float4 u0 = p[0], u1 = p[1];
                v[0]=g*u0.x; v[1]=g*u0.y; v[2]=g*u0.z; v[3]=g*u0.w;
                v[4]=g*u1.x; v[5]=g*u1.y; v[6]=g*u1.z; v[7]=g*u1.w;
                split8(v, ah[l][kt], al[l][kt]);
            }
            const int r0 = l * 64 + j0;
            float4v bi = *(const float4v*)(bih0 + r0);
            float4v bh = *(const float4v*)(bhh0 + r0);
            biasv[l] = (bi + bh) * g;
        } else {
            #pragma unroll
            for (int kt = 0; kt < 4; ++kt) {
                const float* base = (kt < 2) ? (Wih1 + row * HCELLS + kt * 32)
                                             : (Whh1 + row * HCELLS + (kt - 2) * 32);
                const float4* p = (const float4*)(base + q * 8);
                float4 u0 = p[0], u1 = p[1];
                v[0]=g*u0.x; v[1]=g*u0.y; v[2]=g*u0.z; v[3]=g*u0.w;
                v[4]=g*u1.x; v[5]=g*u1.y; v[6]=g*u1.z; v[7]=g*u1.w;
                split8(v, ah[l][kt], al[l][kt]);
            }
            const int r0 = l * 64 + j0;
            float4v bi = *(const float4v*)(bih1 + r0);
            float4v bh = *(const float4v*)(bhh1 + r0);
            biasv[l] = (bi + bh) * g;
        }
    }

    // ---------------- zero LDS, stage x(0) -> slot 0 ----------------
    for (int i = tid; i < SB_HALFS / 2; i += TB) ((int*)SB)[i] = 0;

    const int nx = tid >> 4;            // x-loader role (grp0 threads: tid<256)
    const int kp = (tid & 15) * 2;
    const float* xp0 = (grp == 0) ? (x + (size_t)(b0 + nx) * T * DIN + kp) : nullptr;
    __syncthreads();
    if (grp == 0) {
        float2 xv = *(const float2*)xp0;
        half2v hi = {(_Float16)xv.x, (_Float16)xv.y};
        *(half2v*)&SB[XH_OFF + xidx(0, nx, kp)] = hi;
    }
    __syncthreads();

    float cs[4] = {0, 0, 0, 0};
    float hlast[4];
    const float* xp = (grp == 0) ? (xp0 + DIN) : nullptr;

    // ---------------- pipelined time loop: ONE barrier per region ----------------
    // region t: A computes L0(t); B computes L1(t-1) (t>=1); v(tau) lives in slot (tau+1)&1
    #pragma unroll 2
    for (int t = 0; t < T; ++t) {
        const int pr = t & 1, pw = pr ^ 1;

        if (grp == 0) {
            // prefetch x(t+1)
            float2 xv;
            const bool havex = (t + 1 < T);
            if (havex) xv = *(const float2*)xp;
            xp += DIN;

            float4v acc[4];
            #pragma unroll
            for (int l = 0; l < 4; ++l) acc[l] = biasv[l];
            // kt=0: x(t) @ X[pr]
            {
                half8 bh = *(const half8*)&SB[XH_OFF + xidx(pr, n16, q * 8)];
                #pragma unroll
                for (int l = 0; l < 4; ++l) {
                    acc[l] = __builtin_amdgcn_mfma_f32_16x16x32_f16(ah[l][0], bh, acc[l], 0, 0, 0);
                    acc[l] = __builtin_amdgcn_mfma_f32_16x16x32_f16(al[l][0], bh, acc[l], 0, 0, 0);
                }
            }
            // kt=1,2: h0(t-1) @ H0[pr]
            #pragma unroll
            for (int kt = 1; kt < 3; ++kt) {
                half8 bh = *(const half8*)&SB[H0H_OFF + hidx(pr, n16, (kt - 1) * 32 + q * 8)];
                #pragma unroll
                for (int l = 0; l < 4; ++l) {
                    acc[l] = __builtin_amdgcn_mfma_f32_16x16x32_f16(ah[l][kt], bh, acc[l], 0, 0, 0);
                    acc[l] = __builtin_amdgcn_mfma_f32_16x16x32_f16(al[l][kt], bh, acc[l], 0, 0, 0);
                }
            }
            half4v hh;
            cell_update(acc, cs, hh, nullptr);
            *(half4v*)&SB[H0H_OFF + hidx(pw, n16, j0)] = hh;   // h0(t) -> slot pw
            // stage x(t+1) -> X[pw]
            if (havex) {
                half2v hi = {(_Float16)xv.x, (_Float16)xv.y};
                *(half2v*)&SB[XH_OFF + xidx(pw, nx, kp)] = hi;
            }
        } else if (t > 0) {
            // L1(t-1): h0(t-1) @ H0[pr], h1(t-2) @ H1[pw]
            float4v acc[4];
            #pragma unroll
            for (int l = 0; l < 4; ++l) acc[l] = biasv[l];
            #pragma unroll
            for (int kt = 0; kt < 4; ++kt) {
                half8 bh = (kt < 2)
                    ? *(const half8*)&SB[H0H_OFF + hidx(pr, n16, kt * 32 + q * 8)]
                    : *(const half8*)&SB[H1H_OFF + hidx(pw, n16, (kt - 2) * 32 + q * 8)];
                #pragma unroll
                for (int l = 0; l < 4; ++l) {
                    acc[l] = __builtin_amdgcn_mfma_f32_16x16x32_f16(ah[l][kt], bh, acc[l], 0, 0, 0);
                    acc[l] = __builtin_amdgcn_mfma_f32_16x16x32_f16(al[l][kt], bh, acc[l], 0, 0, 0);
                }
            }
            half4v hh;
            cell_update(acc, cs, hh, nullptr);
            *(half4v*)&SB[H1H_OFF + hidx(pr, n16, j0)] = hh;   // h1(t-1) -> slot pr
        }
        __syncthreads();
    }

    // ---------------- epilogue: B computes L1(T-1) ----------------
    // h0(T-1) in slot 0 ; h1(T-2) in slot 1   (T even)
    float* h1f = HS;             // [16][68]
    float* hid = HS + 16 * 68;   // [16][33]
    if (grp == 1) {
        float4v acc[4];
        #pragma unroll
        for (int l = 0; l < 4; ++l) acc[l] = biasv[l];
        #pragma unroll
        for (int kt = 0; kt < 4; ++kt) {
            half8 bh = (kt < 2)
                ? *(const half8*)&SB[H0H_OFF + hidx(0, n16, kt * 32 + q * 8)]
                : *(const half8*)&SB[H1H_OFF + hidx(1, n16, (kt - 2) * 32 + q * 8)];
            #pragma unroll
            for (int l = 0; l < 4; ++l) {
                acc[l] = __builtin_amdgcn_mfma_f32_16x16x32_f16(ah[l][kt], bh, acc[l], 0, 0, 0);
                acc[l] = __builtin_amdgcn_mfma_f32_16x16x32_f16(al[l][kt], bh, acc[l], 0, 0, 0);
            }
        }
        half4v hh;
        cell_update(acc, cs, hh, hlast);
        *(float4*)&h1f[n16 * 68 + j0] = *(const float4*)hlast;
    }
    __syncthreads();

    // ---------------- head: relu(h1 @ W1^T + b1) @ W2^T + b2 ----------------
    if (tid < 256) {
        const int n2 = tid >> 4, m = tid & 15;
        float s0 = b1[m], s1 = b1[m + 16];
        const float* w0p = W1 + m * HCELLS;
        const float* w1p = W1 + (m + 16) * HCELLS;
        #pragma unroll
        for (int j = 0; j < HCELLS; ++j) {
            float hv = h1f[n2 * 68 + j];
            s0 = fmaf(w0p[j], hv, s0);
            s1 = fmaf(w1p[j], hv, s1);
        }
        hid[n2 * 33 + m]      = fmaxf(s0, 0.0f);
        hid[n2 * 33 + m + 16] = fmaxf(s1, 0.0f);
    }
    __syncthreads();

    if (tid < NB) {
        float s = b2[0];
        #pragma unroll
        for (int m = 0; m < 32; ++m) s = fmaf(W2[m], hid[tid * 33 + m], s);
        out[b0 + tid] = s;
    }
}

extern "C" void kernel_launch(void* const* d_in, const int* in_sizes, int n_in,
                              void* d_out, int out_size, void* d_ws, size_t ws_size,
                              hipStream_t stream) {
    const float* x    = (const float*)d_in[0];
    const float* Wih0 = (const float*)d_in[1];
    const float* Whh0 = (const float*)d_in[2];
    const float* bih0 = (const float*)d_in[3];
    const float* bhh0 = (const float*)d_in[4];
    const float* Wih1 = (const float*)d_in[5];
    const float* Whh1 = (const float*)d_in[6];
    const float* bih1 = (const float*)d_in[7];
    const float* bhh1 = (const float*)d_in[8];
    const float* W1   = (const float*)d_in[9];
    const float* b1   = (const float*)d_in[10];
    const float* W2   = (const float*)d_in[11];
    const float* b2   = (const float*)d_in[12];
    float* out = (float*)d_out;

    hipLaunchKernelGGL(lstm2_mfma_kernel, dim3(GRID), dim3(TB), 0, stream,
                       x, Wih0, Whh0, bih0, bhh0, Wih1, Whh1, bih1, bhh1,
                       W1, b1, W2, b2, out);
}

// Round 7
// 447.481 us; speedup vs baseline: 2.4429x; 1.1823x over previous
//
#include <hip/hip_runtime.h>

#define T       512
#define DIN     32
#define HCELLS  64
#define NB      16      // batch elems per block (MFMA N dim)
#define TB      512     // 8 waves: group A = waves 0-3 (layer 0), group B = waves 4-7 (layer 1)
#define GRID    64      // 1024 / NB

typedef _Float16 half8  __attribute__((ext_vector_type(8)));
typedef _Float16 half4v __attribute__((ext_vector_type(4)));
typedef _Float16 half2v __attribute__((ext_vector_type(2)));
typedef float    float4v __attribute__((ext_vector_type(4)));

// LDS fp16 buffers (hi only). Weights single-fp16 too (round 7: A-lo dropped —
// error budget shows B-side 2^-11 dominates; A-lo was buying 2^-22 we don't need).
#define STRX    40      // x rows: 32 + 8 pad
#define STRH    72      // h rows: 64 + 8 pad
#define XH_OFF  0                       // [2][16][STRX]
#define H0H_OFF (2*16*STRX)             // [2][16][STRH]
#define H1H_OFF (H0H_OFF + 2*16*STRH)
#define SB_HALFS (H1H_OFF + 2*16*STRH)

#define LOG2E   1.44269504f
#define SLOG2E  2.88539008f     // 2*log2(e); cell state kept as cs = SLOG2E * c

__device__ __forceinline__ int xidx(int p, int n, int k) { return (p * 16 + n) * STRX + k; }
__device__ __forceinline__ int hidx(int p, int n, int k) { return (p * 16 + n) * STRH + k; }

__device__ __forceinline__ void cvt8(const float* v, half8& hi) {
    #pragma unroll
    for (int e = 0; e < 8; ++e) hi[e] = (_Float16)v[e];
}

// Scaled-domain LSTM cell update (gate scales folded into weights):
//   acc[0]=-log2e*zi, acc[1]=-log2e*zf, acc[2]=2log2e*zg, acc[3]=-log2e*zo ; cs = 2log2e*c
__device__ __forceinline__ void cell_update(const float4v acc[4], float* cs,
                                            half4v& hh, float* hout)
{
    #pragma unroll
    for (int r = 0; r < 4; ++r) {
        float ei = __builtin_amdgcn_exp2f(acc[0][r]);   // e^{-zi}
        float ef = __builtin_amdgcn_exp2f(acc[1][r]);   // e^{-zf}
        float G2 = __builtin_amdgcn_exp2f(acc[2][r]);   // e^{2 zg}
        float I  = 1.0f + ei, F = 1.0f + ef;
        float Gp = 1.0f + G2;
        float Gms = fmaf(SLOG2E, G2, -SLOG2E);          // s*(G2-1)
        float P   = I * Gp;
        float num = fmaf(F, Gms, cs[r] * P);
        float csn = num * __builtin_amdgcn_rcpf(F * P);
        csn = fminf(fmaxf(csn, -50.0f), 50.0f);
        cs[r] = csn;
        float eo = __builtin_amdgcn_exp2f(acc[3][r]);   // e^{-zo}
        float C2 = __builtin_amdgcn_exp2f(csn);         // e^{2 c'}
        float O  = 1.0f + eo;
        float Cp = 1.0f + C2, Cm = C2 - 1.0f;
        float h  = Cm * __builtin_amdgcn_rcpf(O * Cp);
        if (hout) hout[r] = h;
        hh[r] = (_Float16)h;
    }
}

__global__ void __launch_bounds__(TB, 2)
lstm2_mfma_kernel(const float* __restrict__ x,
                  const float* __restrict__ Wih0, const float* __restrict__ Whh0,
                  const float* __restrict__ bih0, const float* __restrict__ bhh0,
                  const float* __restrict__ Wih1, const float* __restrict__ Whh1,
                  const float* __restrict__ bih1, const float* __restrict__ bhh1,
                  const float* __restrict__ W1,   const float* __restrict__ b1,
                  const float* __restrict__ W2,   const float* __restrict__ b2,
                  float* __restrict__ out)
{
    const int tid  = threadIdx.x;
    const int wid  = tid >> 6;
    const int grp  = wid >> 2;          // 0 = layer-0 group, 1 = layer-1 group
    const int wl   = wid & 3;           // local wave in group
    const int lane = tid & 63;
    const int n16  = lane & 15;         // MFMA free index / local batch
    const int q    = lane >> 4;         // quad 0..3
    const int j0   = wl * 16 + q * 4;   // this thread's hidden-unit base (4 rows)
    const int b0   = blockIdx.x * NB;

    __shared__ __align__(16) _Float16 SB[SB_HALFS];
    __shared__ __align__(16) float HS[16 * 68 + 16 * 33];

    const float gsc[4] = {-LOG2E, -LOG2E, SLOG2E, -LOG2E};

    // ---------------- per-group weight fragments (single fp16) ----------------
    half8 ah[4][4];
    float4v biasv[4];

    #pragma unroll
    for (int l = 0; l < 4; ++l) {
        const int row = (l * 4 + wl) * 16 + n16;
        const float g = gsc[l];
        float v[8];
        if (grp == 0) {
            {
                const float4* p = (const float4*)(Wih0 + row * DIN + q * 8);
                float4 u0 = p[0], u1 = p[1];
                v[0]=g*u0.x; v[1]=g*u0.y; v[2]=g*u0.z; v[3]=g*u0.w;
                v[4]=g*u1.x; v[5]=g*u1.y; v[6]=g*u1.z; v[7]=g*u1.w;
                cvt8(v, ah[l][0]);
            }
            #pragma unroll
            for (int kt = 1; kt < 3; ++kt) {
                const float4* p = (const float4*)(Whh0 + row * HCELLS + (kt - 1) * 32 + q * 8);
                float4 u0 = p[0], u1 = p[1];
                v[0]=g*u0.x; v[1]=g*u0.y; v[2]=g*u0.z; v[3]=g*u0.w;
                v[4]=g*u1.x; v[5]=g*u1.y; v[6]=g*u1.z; v[7]=g*u1.w;
                cvt8(v, ah[l][kt]);
            }
            const int r0 = l * 64 + j0;
            float4v bi = *(const float4v*)(bih0 + r0);
            float4v bh = *(const float4v*)(bhh0 + r0);
            biasv[l] = (bi + bh) * g;
        } else {
            #pragma unroll
            for (int kt = 0; kt < 4; ++kt) {
                const float* base = (kt < 2) ? (Wih1 + row * HCELLS + kt * 32)
                                             : (Whh1 + row * HCELLS + (kt - 2) * 32);
                const float4* p = (const float4*)(base + q * 8);
                float4 u0 = p[0], u1 = p[1];
                v[0]=g*u0.x; v[1]=g*u0.y; v[2]=g*u0.z; v[3]=g*u0.w;
                v[4]=g*u1.x; v[5]=g*u1.y; v[6]=g*u1.z; v[7]=g*u1.w;
                cvt8(v, ah[l][kt]);
            }
            const int r0 = l * 64 + j0;
            float4v bi = *(const float4v*)(bih1 + r0);
            float4v bh = *(const float4v*)(bhh1 + r0);
            biasv[l] = (bi + bh) * g;
        }
    }

    // ---------------- zero LDS, stage x(0) -> slot 0 ----------------
    for (int i = tid; i < SB_HALFS / 2; i += TB) ((int*)SB)[i] = 0;

    const int nx = tid >> 4;            // x-loader role (grp0 threads: tid<256)
    const int kp = (tid & 15) * 2;
    const float* xp0 = (grp == 0) ? (x + (size_t)(b0 + nx) * T * DIN + kp) : nullptr;
    __syncthreads();
    if (grp == 0) {
        float2 xv = *(const float2*)xp0;
        half2v hi = {(_Float16)xv.x, (_Float16)xv.y};
        *(half2v*)&SB[XH_OFF + xidx(0, nx, kp)] = hi;
    }
    __syncthreads();

    float cs[4] = {0, 0, 0, 0};
    float hlast[4];
    const float* xp = (grp == 0) ? (xp0 + DIN) : nullptr;

    // ---------------- pipelined time loop: ONE barrier per region ----------------
    // region t: A computes L0(t); B computes L1(t-1) (t>=1); v(tau) lives in slot (tau+1)&1
    #pragma unroll 2
    for (int t = 0; t < T; ++t) {
        const int pr = t & 1, pw = pr ^ 1;

        if (grp == 0) {
            // prefetch x(t+1)
            float2 xv;
            const bool havex = (t + 1 < T);
            if (havex) xv = *(const float2*)xp;
            xp += DIN;

            float4v acc[4];
            #pragma unroll
            for (int l = 0; l < 4; ++l) acc[l] = biasv[l];
            // kt=0: x(t) @ X[pr]
            {
                half8 bh = *(const half8*)&SB[XH_OFF + xidx(pr, n16, q * 8)];
                #pragma unroll
                for (int l = 0; l < 4; ++l)
                    acc[l] = __builtin_amdgcn_mfma_f32_16x16x32_f16(ah[l][0], bh, acc[l], 0, 0, 0);
            }
            // kt=1,2: h0(t-1) @ H0[pr]
            #pragma unroll
            for (int kt = 1; kt < 3; ++kt) {
                half8 bh = *(const half8*)&SB[H0H_OFF + hidx(pr, n16, (kt - 1) * 32 + q * 8)];
                #pragma unroll
                for (int l = 0; l < 4; ++l)
                    acc[l] = __builtin_amdgcn_mfma_f32_16x16x32_f16(ah[l][kt], bh, acc[l], 0, 0, 0);
            }
            half4v hh;
            cell_update(acc, cs, hh, nullptr);
            *(half4v*)&SB[H0H_OFF + hidx(pw, n16, j0)] = hh;   // h0(t) -> slot pw
            // stage x(t+1) -> X[pw]
            if (havex) {
                half2v hi = {(_Float16)xv.x, (_Float16)xv.y};
                *(half2v*)&SB[XH_OFF + xidx(pw, nx, kp)] = hi;
            }
        } else if (t > 0) {
            // L1(t-1): h0(t-1) @ H0[pr], h1(t-2) @ H1[pw]
            float4v acc[4];
            #pragma unroll
            for (int l = 0; l < 4; ++l) acc[l] = biasv[l];
            #pragma unroll
            for (int kt = 0; kt < 4; ++kt) {
                half8 bh = (kt < 2)
                    ? *(const half8*)&SB[H0H_OFF + hidx(pr, n16, kt * 32 + q * 8)]
                    : *(const half8*)&SB[H1H_OFF + hidx(pw, n16, (kt - 2) * 32 + q * 8)];
                #pragma unroll
                for (int l = 0; l < 4; ++l)
                    acc[l] = __builtin_amdgcn_mfma_f32_16x16x32_f16(ah[l][kt], bh, acc[l], 0, 0, 0);
            }
            half4v hh;
            cell_update(acc, cs, hh, nullptr);
            *(half4v*)&SB[H1H_OFF + hidx(pr, n16, j0)] = hh;   // h1(t-1) -> slot pr
        }
        __syncthreads();
    }

    // ---------------- epilogue: B computes L1(T-1) ----------------
    // h0(T-1) in slot 0 ; h1(T-2) in slot 1   (T even)
    float* h1f = HS;             // [16][68]
    float* hid = HS + 16 * 68;   // [16][33]
    if (grp == 1) {
        float4v acc[4];
        #pragma unroll
        for (int l = 0; l < 4; ++l) acc[l] = biasv[l];
        #pragma unroll
        for (int kt = 0; kt < 4; ++kt) {
            half8 bh = (kt < 2)
                ? *(const half8*)&SB[H0H_OFF + hidx(0, n16, kt * 32 + q * 8)]
                : *(const half8*)&SB[H1H_OFF + hidx(1, n16, (kt - 2) * 32 + q * 8)];
            #pragma unroll
            for (int l = 0; l < 4; ++l)
                acc[l] = __builtin_amdgcn_mfma_f32_16x16x32_f16(ah[l][kt], bh, acc[l], 0, 0, 0);
        }
        half4v hh;
        cell_update(acc, cs, hh, hlast);
        *(float4*)&h1f[n16 * 68 + j0] = *(const float4*)hlast;
    }
    __syncthreads();

    // ---------------- head: relu(h1 @ W1^T + b1) @ W2^T + b2 ----------------
    if (tid < 256) {
        const int n2 = tid >> 4, m = tid & 15;
        float s0 = b1[m], s1 = b1[m + 16];
        const float* w0p = W1 + m * HCELLS;
        const float* w1p = W1 + (m + 16) * HCELLS;
        #pragma unroll
        for (int j = 0; j < HCELLS; ++j) {
            float hv = h1f[n2 * 68 + j];
            s0 = fmaf(w0p[j], hv, s0);
            s1 = fmaf(w1p[j], hv, s1);
        }
        hid[n2 * 33 + m]      = fmaxf(s0, 0.0f);
        hid[n2 * 33 + m + 16] = fmaxf(s1, 0.0f);
    }
    __syncthreads();

    if (tid < NB) {
        float s = b2[0];
        #pragma unroll
        for (int m = 0; m < 32; ++m) s = fmaf(W2[m], hid[tid * 33 + m], s);
        out[b0 + tid] = s;
    }
}

extern "C" void kernel_launch(void* const* d_in, const int* in_sizes, int n_in,
                              void* d_out, int out_size, void* d_ws, size_t ws_size,
                              hipStream_t stream) {
    const float* x    = (const float*)d_in[0];
    const float* Wih0 = (const float*)d_in[1];
    const float* Whh0 = (const float*)d_in[2];
    const float* bih0 = (const float*)d_in[3];
    const float* bhh0 = (const float*)d_in[4];
    const float* Wih1 = (const float*)d_in[5];
    const float* Whh1 = (const float*)d_in[6];
    const float* bih1 = (const float*)d_in[7];
    const float* bhh1 = (const float*)d_in[8];
    const float* W1   = (const float*)d_in[9];
    const float* b1   = (const float*)d_in[10];
    const float* W2   = (const float*)d_in[11];
    const float* b2   = (const float*)d_in[12];
    float* out = (float*)d_out;

    hipLaunchKernelGGL(lstm2_mfma_kernel, dim3(GRID), dim3(TB), 0, stream,
                       x, Wih0, Whh0, bih0, bhh0, Wih1, Whh1, bih1, bhh1,
                       W1, b1, W2, b2, out);
}